// Round 1
// baseline (2204.295 us; speedup 1.0000x reference)
//
#include <hip/hip_runtime.h>
#include <hip/hip_bf16.h>

#define N_NODES 50000
#define N_EDGES 800000
#define IN_DIM 128
#define HID_DIM 256
#define OUT_DIM 40

// ---- workspace layout (bytes) ----
// cnt   : [0,        200192)   50000 int
// agg1  : [200192,   25800192) 50000*128 f32
// acc2  : [25800192, 33800192) 50000*40  f32
// h     : [33800192, 85000192) 50000*256 f32
// p2    : [85000192, 93000192) 50000*40  f32
// r2    : [93000192, 101000192)50000*40  f32
#define OFF_AGG1 200192
#define OFF_ACC2 25800192
#define OFF_H    33800192
#define OFF_P2   85000192
#define OFF_R2   93000192
#define ZERO_BYTES 33800192   // cnt + agg1 + acc2

__device__ __forceinline__ void atomAddF(float* p, float v) {
  unsafeAtomicAdd(p, v);  // native global_atomic_add_f32, device scope
}

__global__ void k_count(const int* __restrict__ dst, int* __restrict__ cnt) {
  int e = blockIdx.x * blockDim.x + threadIdx.x;
  if (e < N_EDGES) atomicAdd(&cnt[dst[e]], 1);
}

// one edge handled by 32 threads, 4 channels each (float4)
__global__ void k_scatter1(const int* __restrict__ src, const int* __restrict__ dst,
                           const float* __restrict__ x, float* __restrict__ agg1) {
  int t = blockIdx.x * blockDim.x + threadIdx.x;
  int e = t >> 5;
  if (e >= N_EDGES) return;
  int c4 = (t & 31) << 2;
  int s = src[e], d = dst[e];
  float4 v = *(const float4*)(x + (size_t)s * IN_DIM + c4);
  float* a = agg1 + (size_t)d * IN_DIM + c4;
  atomAddF(a + 0, v.x);
  atomAddF(a + 1, v.y);
  atomAddF(a + 2, v.z);
  atomAddF(a + 3, v.w);
}

// h = relu(agg1*inv @ W1l + x @ W1r + b1)
// block: 256 threads = 256 output cols; 16 rows per block staged in LDS
__global__ __launch_bounds__(256) void k_gemm1(
    const float* __restrict__ x, const float* __restrict__ agg1,
    const int* __restrict__ cnt,
    const float* __restrict__ W1l, const float* __restrict__ W1r,
    const float* __restrict__ b1, float* __restrict__ h) {
  __shared__ float la[16][IN_DIM];
  __shared__ float lx[16][IN_DIM];
  __shared__ float linv[16];
  const int tid = threadIdx.x;
  const int row0 = blockIdx.x * 16;

  // stage 16 rows of x and agg1 (float4: 512 loads over 256 threads)
  for (int i = tid; i < 16 * (IN_DIM / 4); i += 256) {
    int r = i >> 5;              // 32 float4 per row
    int c4 = (i & 31) << 2;
    size_t off = (size_t)(row0 + r) * IN_DIM + c4;
    *(float4*)&lx[r][c4] = *(const float4*)(x + off);
    *(float4*)&la[r][c4] = *(const float4*)(agg1 + off);
  }
  if (tid < 16) linv[tid] = 1.0f / (float)max(cnt[row0 + tid], 1);
  __syncthreads();

  float acc_a[16], acc_x[16];
#pragma unroll
  for (int r = 0; r < 16; ++r) { acc_a[r] = 0.f; acc_x[r] = 0.f; }

  for (int k = 0; k < IN_DIM; k += 4) {
    float wl[4], wr[4];
#pragma unroll
    for (int i = 0; i < 4; ++i) {
      wl[i] = W1l[(size_t)(k + i) * HID_DIM + tid];
      wr[i] = W1r[(size_t)(k + i) * HID_DIM + tid];
    }
#pragma unroll
    for (int r = 0; r < 16; ++r) {
      float4 a4 = *(const float4*)&la[r][k];   // broadcast LDS read
      float4 x4 = *(const float4*)&lx[r][k];
      acc_a[r] += a4.x * wl[0] + a4.y * wl[1] + a4.z * wl[2] + a4.w * wl[3];
      acc_x[r] += x4.x * wr[0] + x4.y * wr[1] + x4.z * wr[2] + x4.w * wr[3];
    }
  }

  float bb = b1[tid];
#pragma unroll
  for (int r = 0; r < 16; ++r) {
    float v = acc_a[r] * linv[r] + acc_x[r] + bb;
    h[(size_t)(row0 + r) * HID_DIM + tid] = fmaxf(v, 0.f);
  }
}

// p2 = h @ W2l ; r2 = h @ W2r + b2   (one thread per node row)
__global__ __launch_bounds__(256) void k_gemm2(
    const float* __restrict__ h,
    const float* __restrict__ W2l, const float* __restrict__ W2r,
    const float* __restrict__ b2,
    float* __restrict__ p2, float* __restrict__ r2) {
  __shared__ float wl[HID_DIM * OUT_DIM];  // 40 KiB
  __shared__ float wr[HID_DIM * OUT_DIM];  // 40 KiB
  __shared__ float bb[OUT_DIM];
  const int tid = threadIdx.x;
  for (int i = tid * 4; i < HID_DIM * OUT_DIM; i += 256 * 4) {
    *(float4*)&wl[i] = *(const float4*)&W2l[i];
    *(float4*)&wr[i] = *(const float4*)&W2r[i];
  }
  if (tid < OUT_DIM) bb[tid] = b2[tid];
  __syncthreads();

  int row = blockIdx.x * 256 + tid;
  if (row >= N_NODES) return;

  float accl[OUT_DIM], accr[OUT_DIM];
#pragma unroll
  for (int j = 0; j < OUT_DIM; ++j) { accl[j] = 0.f; accr[j] = 0.f; }

  const float* hrow = h + (size_t)row * HID_DIM;
  for (int k = 0; k < HID_DIM; k += 4) {
    float4 h4 = *(const float4*)(hrow + k);
#pragma unroll
    for (int i = 0; i < 4; ++i) {
      float hv = (&h4.x)[i];
      const float* wlk = &wl[(k + i) * OUT_DIM];
      const float* wrk = &wr[(k + i) * OUT_DIM];
#pragma unroll
      for (int j4 = 0; j4 < OUT_DIM; j4 += 4) {
        float4 w4l = *(const float4*)&wlk[j4];  // broadcast LDS read
        float4 w4r = *(const float4*)&wrk[j4];
        accl[j4 + 0] += hv * w4l.x; accl[j4 + 1] += hv * w4l.y;
        accl[j4 + 2] += hv * w4l.z; accl[j4 + 3] += hv * w4l.w;
        accr[j4 + 0] += hv * w4r.x; accr[j4 + 1] += hv * w4r.y;
        accr[j4 + 2] += hv * w4r.z; accr[j4 + 3] += hv * w4r.w;
      }
    }
  }

  float* pr = p2 + (size_t)row * OUT_DIM;
  float* rr = r2 + (size_t)row * OUT_DIM;
#pragma unroll
  for (int j4 = 0; j4 < OUT_DIM; j4 += 4) {
    float4 vp = make_float4(accl[j4], accl[j4 + 1], accl[j4 + 2], accl[j4 + 3]);
    float4 vr = make_float4(accr[j4] + bb[j4], accr[j4 + 1] + bb[j4 + 1],
                            accr[j4 + 2] + bb[j4 + 2], accr[j4 + 3] + bb[j4 + 3]);
    *(float4*)(pr + j4) = vp;
    *(float4*)(rr + j4) = vr;
  }
}

// one edge handled by 10 threads, 4 channels each
__global__ void k_scatter2(const int* __restrict__ src, const int* __restrict__ dst,
                           const float* __restrict__ p2, float* __restrict__ acc2) {
  int t = blockIdx.x * blockDim.x + threadIdx.x;
  int e = t / 10;
  if (e >= N_EDGES) return;
  int c4 = (t - e * 10) * 4;
  int s = src[e], d = dst[e];
  float4 v = *(const float4*)(p2 + (size_t)s * OUT_DIM + c4);
  float* a = acc2 + (size_t)d * OUT_DIM + c4;
  atomAddF(a + 0, v.x);
  atomAddF(a + 1, v.y);
  atomAddF(a + 2, v.z);
  atomAddF(a + 3, v.w);
}

// out = log_softmax(acc2*inv + r2)
__global__ void k_final(const float* __restrict__ acc2, const float* __restrict__ r2,
                        const int* __restrict__ cnt, float* __restrict__ out) {
  int row = blockIdx.x * blockDim.x + threadIdx.x;
  if (row >= N_NODES) return;
  float inv = 1.0f / (float)max(cnt[row], 1);
  const float* a = acc2 + (size_t)row * OUT_DIM;
  const float* r = r2 + (size_t)row * OUT_DIM;
  float v[OUT_DIM];
  float m = -1e30f;
#pragma unroll
  for (int j4 = 0; j4 < OUT_DIM; j4 += 4) {
    float4 av = *(const float4*)(a + j4);
    float4 rv = *(const float4*)(r + j4);
    v[j4 + 0] = av.x * inv + rv.x;
    v[j4 + 1] = av.y * inv + rv.y;
    v[j4 + 2] = av.z * inv + rv.z;
    v[j4 + 3] = av.w * inv + rv.w;
    m = fmaxf(m, fmaxf(fmaxf(v[j4], v[j4 + 1]), fmaxf(v[j4 + 2], v[j4 + 3])));
  }
  float s = 0.f;
#pragma unroll
  for (int j = 0; j < OUT_DIM; ++j) s += __expf(v[j] - m);
  float ls = __logf(s) + m;
  float* o = out + (size_t)row * OUT_DIM;
#pragma unroll
  for (int j4 = 0; j4 < OUT_DIM; j4 += 4) {
    float4 w = make_float4(v[j4] - ls, v[j4 + 1] - ls, v[j4 + 2] - ls, v[j4 + 3] - ls);
    *(float4*)(o + j4) = w;
  }
}

extern "C" void kernel_launch(void* const* d_in, const int* in_sizes, int n_in,
                              void* d_out, int out_size, void* d_ws, size_t ws_size,
                              hipStream_t stream) {
  const float* x   = (const float*)d_in[0];
  const int*   ei  = (const int*)d_in[1];   // [2, N_EDGES] int32
  const float* W1l = (const float*)d_in[2];
  const float* W1r = (const float*)d_in[3];
  const float* b1  = (const float*)d_in[4];
  const float* W2l = (const float*)d_in[5];
  const float* W2r = (const float*)d_in[6];
  const float* b2  = (const float*)d_in[7];
  float* out = (float*)d_out;

  const int* src = ei;
  const int* dst = ei + N_EDGES;

  char* ws = (char*)d_ws;
  int*   cnt  = (int*)ws;
  float* agg1 = (float*)(ws + OFF_AGG1);
  float* acc2 = (float*)(ws + OFF_ACC2);
  float* h    = (float*)(ws + OFF_H);
  float* p2   = (float*)(ws + OFF_P2);
  float* r2   = (float*)(ws + OFF_R2);

  hipMemsetAsync(d_ws, 0, ZERO_BYTES, stream);

  k_count<<<(N_EDGES + 255) / 256, 256, 0, stream>>>(dst, cnt);
  k_scatter1<<<(N_EDGES * 32) / 256, 256, 0, stream>>>(src, dst, x, agg1);
  k_gemm1<<<N_NODES / 16, 256, 0, stream>>>(x, agg1, cnt, W1l, W1r, b1, h);
  k_gemm2<<<(N_NODES + 255) / 256, 256, 0, stream>>>(h, W2l, W2r, b2, p2, r2);
  k_scatter2<<<(N_EDGES * 10 + 255) / 256, 256, 0, stream>>>(src, dst, p2, acc2);
  k_final<<<(N_NODES + 255) / 256, 256, 0, stream>>>(acc2, r2, cnt, out);
}

// Round 2
// 621.074 us; speedup vs baseline: 3.5492x; 3.5492x over previous
//
#include <hip/hip_runtime.h>
#include <hip/hip_bf16.h>

#define N_NODES 50000
#define N_EDGES 800000
#define IN_DIM 128
#define HID_DIM 256
#define OUT_DIM 40

// ---- workspace layout (bytes) ----
#define OFF_CNT   0          // 50000 int   (200000 B)  -- zeroed each call
#define OFF_RP    200192     // 50001 int   row_ptr
#define OFF_CUR   400640     // 50001 int   cursor (copy of row_ptr)
#define OFF_ESRC  601088     // 800000 int  dst-sorted src ids (3.2 MB)
#define OFF_AGG1  3801088    // 50000*128 f32, pre-divided by cnt (25.6 MB)
#define OFF_H     29401088   // 50000*256 f32 (51.2 MB)
#define OFF_P2    80601088   // 50000*40 f32 (8 MB)
#define OFF_R2    88601088   // 50000*40 f32 (8 MB)
// total 96.6 MB

__global__ void k_count(const int* __restrict__ dst, int* __restrict__ cnt) {
  int e = blockIdx.x * blockDim.x + threadIdx.x;
  if (e < N_EDGES) atomicAdd(&cnt[dst[e]], 1);
}

// single block: slice-sum -> block scan -> per-slice running prefix
#define SLICE 49   // 1024*49 = 50176 >= 50000
__global__ __launch_bounds__(1024) void k_scan(const int* __restrict__ cnt,
                                               int* __restrict__ row_ptr,
                                               int* __restrict__ cursor) {
  __shared__ int part[1024];
  int tid = threadIdx.x;
  int lo = tid * SLICE, hi = min(lo + SLICE, N_NODES);
  int s = 0;
  for (int i = lo; i < hi; ++i) s += cnt[i];
  part[tid] = s;
  __syncthreads();
  for (int off = 1; off < 1024; off <<= 1) {
    int t = (tid >= off) ? part[tid - off] : 0;
    __syncthreads();
    part[tid] += t;
    __syncthreads();
  }
  int run = part[tid] - s;   // exclusive prefix at slice start
  for (int i = lo; i < hi; ++i) {
    row_ptr[i] = run;
    cursor[i] = run;
    run += cnt[i];
  }
  if (tid == 1023) row_ptr[N_NODES] = part[1023];
}

__global__ void k_fill(const int* __restrict__ src, const int* __restrict__ dst,
                       int* __restrict__ cursor, int* __restrict__ esrc) {
  int e = blockIdx.x * blockDim.x + threadIdx.x;
  if (e >= N_EDGES) return;
  int p = atomicAdd(&cursor[dst[e]], 1);
  esrc[p] = src[e];
}

// per node: mean-gather of x[src] rows; 128 threads = 128 channels, 2 nodes/block
__global__ __launch_bounds__(256) void k_agg1(const float* __restrict__ x,
    const int* __restrict__ row_ptr, const int* __restrict__ esrc,
    float* __restrict__ agg1) {
  int tid = threadIdx.x;
  int node = blockIdx.x * 2 + (tid >> 7);
  int ch = tid & 127;
  int beg = row_ptr[node], end = row_ptr[node + 1];
  float s = 0.f;
  int e = beg;
  for (; e + 1 < end; e += 2) {
    int s0 = esrc[e], s1 = esrc[e + 1];
    s += x[(size_t)s0 * IN_DIM + ch];
    s += x[(size_t)s1 * IN_DIM + ch];
  }
  if (e < end) s += x[(size_t)esrc[e] * IN_DIM + ch];
  float inv = 1.0f / (float)max(end - beg, 1);
  agg1[(size_t)node * IN_DIM + ch] = s * inv;
}

// h = relu(agg1 @ W1l + x @ W1r + b1)   (agg1 already mean-scaled)
__global__ __launch_bounds__(256) void k_gemm1(
    const float* __restrict__ x, const float* __restrict__ agg1,
    const float* __restrict__ W1l, const float* __restrict__ W1r,
    const float* __restrict__ b1, float* __restrict__ h) {
  __shared__ float la[16][IN_DIM];
  __shared__ float lx[16][IN_DIM];
  const int tid = threadIdx.x;
  const int row0 = blockIdx.x * 16;

  for (int i = tid; i < 16 * (IN_DIM / 4); i += 256) {
    int r = i >> 5;
    int c4 = (i & 31) << 2;
    size_t off = (size_t)(row0 + r) * IN_DIM + c4;
    *(float4*)&lx[r][c4] = *(const float4*)(x + off);
    *(float4*)&la[r][c4] = *(const float4*)(agg1 + off);
  }
  __syncthreads();

  float acc_a[16], acc_x[16];
#pragma unroll
  for (int r = 0; r < 16; ++r) { acc_a[r] = 0.f; acc_x[r] = 0.f; }

  for (int k = 0; k < IN_DIM; k += 4) {
    float wl[4], wr[4];
#pragma unroll
    for (int i = 0; i < 4; ++i) {
      wl[i] = W1l[(size_t)(k + i) * HID_DIM + tid];
      wr[i] = W1r[(size_t)(k + i) * HID_DIM + tid];
    }
#pragma unroll
    for (int r = 0; r < 16; ++r) {
      float4 a4 = *(const float4*)&la[r][k];
      float4 x4 = *(const float4*)&lx[r][k];
      acc_a[r] += a4.x * wl[0] + a4.y * wl[1] + a4.z * wl[2] + a4.w * wl[3];
      acc_x[r] += x4.x * wr[0] + x4.y * wr[1] + x4.z * wr[2] + x4.w * wr[3];
    }
  }

  float bb = b1[tid];
#pragma unroll
  for (int r = 0; r < 16; ++r) {
    float v = acc_a[r] + acc_x[r] + bb;
    h[(size_t)(row0 + r) * HID_DIM + tid] = fmaxf(v, 0.f);
  }
}

// p2 = h @ W2l ; r2 = h @ W2r + b2
__global__ __launch_bounds__(256) void k_gemm2(
    const float* __restrict__ h,
    const float* __restrict__ W2l, const float* __restrict__ W2r,
    const float* __restrict__ b2,
    float* __restrict__ p2, float* __restrict__ r2) {
  __shared__ float wl[HID_DIM * OUT_DIM];
  __shared__ float wr[HID_DIM * OUT_DIM];
  __shared__ float bb[OUT_DIM];
  const int tid = threadIdx.x;
  for (int i = tid * 4; i < HID_DIM * OUT_DIM; i += 256 * 4) {
    *(float4*)&wl[i] = *(const float4*)&W2l[i];
    *(float4*)&wr[i] = *(const float4*)&W2r[i];
  }
  if (tid < OUT_DIM) bb[tid] = b2[tid];
  __syncthreads();

  int row = blockIdx.x * 256 + tid;
  if (row >= N_NODES) return;

  float accl[OUT_DIM], accr[OUT_DIM];
#pragma unroll
  for (int j = 0; j < OUT_DIM; ++j) { accl[j] = 0.f; accr[j] = 0.f; }

  const float* hrow = h + (size_t)row * HID_DIM;
  for (int k = 0; k < HID_DIM; k += 4) {
    float4 h4 = *(const float4*)(hrow + k);
#pragma unroll
    for (int i = 0; i < 4; ++i) {
      float hv = (&h4.x)[i];
      const float* wlk = &wl[(k + i) * OUT_DIM];
      const float* wrk = &wr[(k + i) * OUT_DIM];
#pragma unroll
      for (int j4 = 0; j4 < OUT_DIM; j4 += 4) {
        float4 w4l = *(const float4*)&wlk[j4];
        float4 w4r = *(const float4*)&wrk[j4];
        accl[j4 + 0] += hv * w4l.x; accl[j4 + 1] += hv * w4l.y;
        accl[j4 + 2] += hv * w4l.z; accl[j4 + 3] += hv * w4l.w;
        accr[j4 + 0] += hv * w4r.x; accr[j4 + 1] += hv * w4r.y;
        accr[j4 + 2] += hv * w4r.z; accr[j4 + 3] += hv * w4r.w;
      }
    }
  }

  float* pr = p2 + (size_t)row * OUT_DIM;
  float* rr = r2 + (size_t)row * OUT_DIM;
#pragma unroll
  for (int j4 = 0; j4 < OUT_DIM; j4 += 4) {
    float4 vp = make_float4(accl[j4], accl[j4 + 1], accl[j4 + 2], accl[j4 + 3]);
    float4 vr = make_float4(accr[j4] + bb[j4], accr[j4 + 1] + bb[j4 + 1],
                            accr[j4 + 2] + bb[j4 + 2], accr[j4 + 3] + bb[j4 + 3]);
    *(float4*)(pr + j4) = vp;
    *(float4*)(rr + j4) = vr;
  }
}

// fused: out = log_softmax(mean-gather(p2) + r2); one wave per node
__global__ __launch_bounds__(256) void k_agg2(const float* __restrict__ p2,
    const float* __restrict__ r2, const int* __restrict__ row_ptr,
    const int* __restrict__ esrc, float* __restrict__ out) {
  int tid = threadIdx.x;
  int node = blockIdx.x * 4 + (tid >> 6);
  int lane = tid & 63;
  int beg = row_ptr[node], end = row_ptr[node + 1];
  float acc = 0.f;
  if (lane < OUT_DIM) {
    int e = beg;
    for (; e + 1 < end; e += 2) {
      int s0 = esrc[e], s1 = esrc[e + 1];
      acc += p2[(size_t)s0 * OUT_DIM + lane];
      acc += p2[(size_t)s1 * OUT_DIM + lane];
    }
    if (e < end) acc += p2[(size_t)esrc[e] * OUT_DIM + lane];
  }
  float inv = 1.0f / (float)max(end - beg, 1);
  float v = (lane < OUT_DIM) ? acc * inv + r2[(size_t)node * OUT_DIM + lane]
                             : -1e30f;
  float m = v;
#pragma unroll
  for (int o = 32; o; o >>= 1) m = fmaxf(m, __shfl_xor(m, o, 64));
  float ex = (lane < OUT_DIM) ? __expf(v - m) : 0.f;
  float ssum = ex;
#pragma unroll
  for (int o = 32; o; o >>= 1) ssum += __shfl_xor(ssum, o, 64);
  float ls = __logf(ssum) + m;
  if (lane < OUT_DIM) out[(size_t)node * OUT_DIM + lane] = v - ls;
}

extern "C" void kernel_launch(void* const* d_in, const int* in_sizes, int n_in,
                              void* d_out, int out_size, void* d_ws, size_t ws_size,
                              hipStream_t stream) {
  const float* x   = (const float*)d_in[0];
  const int*   ei  = (const int*)d_in[1];
  const float* W1l = (const float*)d_in[2];
  const float* W1r = (const float*)d_in[3];
  const float* b1  = (const float*)d_in[4];
  const float* W2l = (const float*)d_in[5];
  const float* W2r = (const float*)d_in[6];
  const float* b2  = (const float*)d_in[7];
  float* out = (float*)d_out;

  const int* src = ei;
  const int* dst = ei + N_EDGES;

  char* ws = (char*)d_ws;
  int*   cnt     = (int*)(ws + OFF_CNT);
  int*   row_ptr = (int*)(ws + OFF_RP);
  int*   cursor  = (int*)(ws + OFF_CUR);
  int*   esrc    = (int*)(ws + OFF_ESRC);
  float* agg1    = (float*)(ws + OFF_AGG1);
  float* h       = (float*)(ws + OFF_H);
  float* p2      = (float*)(ws + OFF_P2);
  float* r2      = (float*)(ws + OFF_R2);

  hipMemsetAsync(cnt, 0, N_NODES * sizeof(int), stream);

  k_count<<<(N_EDGES + 255) / 256, 256, 0, stream>>>(dst, cnt);
  k_scan<<<1, 1024, 0, stream>>>(cnt, row_ptr, cursor);
  k_fill<<<(N_EDGES + 255) / 256, 256, 0, stream>>>(src, dst, cursor, esrc);
  k_agg1<<<N_NODES / 2, 256, 0, stream>>>(x, row_ptr, esrc, agg1);
  k_gemm1<<<N_NODES / 16, 256, 0, stream>>>(x, agg1, W1l, W1r, b1, h);
  k_gemm2<<<(N_NODES + 255) / 256, 256, 0, stream>>>(h, W2l, W2r, b2, p2, r2);
  k_agg2<<<N_NODES / 4, 256, 0, stream>>>(p2, r2, row_ptr, esrc, out);
}

// Round 4
// 476.753 us; speedup vs baseline: 4.6236x; 1.3027x over previous
//
#include <hip/hip_runtime.h>
#include <hip/hip_bf16.h>

#define N_NODES 50000
#define N_EDGES 800000
#define IN_DIM 128
#define HID_DIM 256
#define OUT_DIM 40
#define M_PAD 50048   // 782 * 64

// ---- workspace layout (bytes), all 16-B aligned ----
#define OFF_CNT   0          // 50000 int
#define OFF_RP    200192     // 50001 int row_ptr
#define OFF_CUR   400640     // 50001 int cursor
#define OFF_ESRC  601088     // 800000 int
#define OFF_AB    3801088    // M_PAD x 256 bf16 (cols 0-127 agg1, 128-255 x) 25.6MB
#define OFF_H     29425664   // M_PAD x 256 bf16
#define OFF_W1T   55050240   // 256 x 256 bf16 (Wt1[n][k])
#define OFF_W2T   55181312   // 80 x 256 bf16
#define OFF_P2    55222272   // M_PAD x 40 bf16
#define OFF_R2    59226112   // M_PAD x 40 f32
// end 67233792

typedef __attribute__((ext_vector_type(8))) short short8;
typedef __attribute__((ext_vector_type(4))) float f32x4;

__device__ __forceinline__ float bfu2f(unsigned u) {
  union { unsigned i; float f; } c; c.i = u << 16; return c.f;
}
__device__ __forceinline__ unsigned f2bfu(float f) {
  union { float f; unsigned i; } c; c.f = f;
  return (c.i + 0x7fffu + ((c.i >> 16) & 1u)) >> 16;   // RNE
}

#define GLOAD_LDS16(g, l)                                                      \
  __builtin_amdgcn_global_load_lds(                                            \
      (const __attribute__((address_space(1))) void*)(g),                      \
      (__attribute__((address_space(3))) void*)(l), 16, 0, 0)

// ---------------- CSR build ----------------
__global__ void k_count(const int* __restrict__ dst, int* __restrict__ cnt) {
  int e = blockIdx.x * blockDim.x + threadIdx.x;
  if (e < N_EDGES) atomicAdd(&cnt[dst[e]], 1);
}

#define SLICE 49
__global__ __launch_bounds__(1024) void k_scan(const int* __restrict__ cnt,
                                               int* __restrict__ row_ptr,
                                               int* __restrict__ cursor) {
  __shared__ int part[1024];
  int tid = threadIdx.x;
  int lo = tid * SLICE, hi = min(lo + SLICE, N_NODES);
  int s = 0;
  for (int i = lo; i < hi; ++i) s += cnt[i];
  part[tid] = s;
  __syncthreads();
  for (int off = 1; off < 1024; off <<= 1) {
    int t = (tid >= off) ? part[tid - off] : 0;
    __syncthreads();
    part[tid] += t;
    __syncthreads();
  }
  int run = part[tid] - s;
  for (int i = lo; i < hi; ++i) {
    row_ptr[i] = run;
    cursor[i] = run;
    run += cnt[i];
  }
  if (tid == 1023) row_ptr[N_NODES] = part[1023];
}

__global__ void k_fill(const int* __restrict__ src, const int* __restrict__ dst,
                       int* __restrict__ cursor, int* __restrict__ esrc) {
  int e = blockIdx.x * blockDim.x + threadIdx.x;
  if (e >= N_EDGES) return;
  int p = atomicAdd(&cursor[dst[e]], 1);
  esrc[p] = src[e];
}

// ---------------- conversions ----------------
// x f32 -> bf16 into AB cols 128..255
__global__ __launch_bounds__(256) void k_convx(const float* __restrict__ x,
                                               char* __restrict__ ABb) {
  int t = blockIdx.x * 256 + threadIdx.x;   // 50000*16 threads, 8 ch each
  int row = t >> 4, c8 = (t & 15) << 3;
  if (row >= N_NODES) return;
  const float* xp = x + (size_t)row * IN_DIM + c8;
  unsigned short o[8];
#pragma unroll
  for (int i = 0; i < 8; ++i) o[i] = (unsigned short)f2bfu(xp[i]);
  // cols 128+c8 .. +8 -> byte offset 256 + c8*2
  *(short8*)(ABb + (size_t)row * 512 + 256 + c8 * 2) = *(short8*)o;
}

// Wt1[n][k] = bf16( k<128 ? W1l[k][n] : W1r[k-128][n] )
__global__ __launch_bounds__(256) void k_convw1(const float* __restrict__ W1l,
                                                const float* __restrict__ W1r,
                                                unsigned short* __restrict__ Wt1) {
  int n = blockIdx.x, k = threadIdx.x;
  float v = (k < 128) ? W1l[(size_t)k * HID_DIM + n]
                      : W1r[(size_t)(k - 128) * HID_DIM + n];
  Wt1[(size_t)n * 256 + k] = (unsigned short)f2bfu(v);
}

// Wt2[n][k] = bf16( n<40 ? W2l[k][n] : W2r[k][n-40] )
__global__ __launch_bounds__(256) void k_convw2(const float* __restrict__ W2l,
                                                const float* __restrict__ W2r,
                                                unsigned short* __restrict__ Wt2) {
  int n = blockIdx.x, k = threadIdx.x;
  float v = (n < OUT_DIM) ? W2l[(size_t)k * OUT_DIM + n]
                          : W2r[(size_t)k * OUT_DIM + (n - OUT_DIM)];
  Wt2[(size_t)n * 256 + k] = (unsigned short)f2bfu(v);
}

// ---------------- aggregation 1 (bf16 gather, mean) ----------------
// wave per node; lane handles 2 channels via one u32 (2 bf16)
__global__ __launch_bounds__(256) void k_agg1(char* __restrict__ ABb,
    const int* __restrict__ row_ptr, const int* __restrict__ esrc) {
  int tid = threadIdx.x;
  int node = blockIdx.x * 4 + (tid >> 6);
  int lane = tid & 63;
  int beg = row_ptr[node], end = row_ptr[node + 1];
  float s0 = 0.f, s1 = 0.f;
  for (int e = beg; e < end; ++e) {
    unsigned v = *(const unsigned*)(ABb + (size_t)esrc[e] * 512 + 256 + lane * 4);
    s0 += bfu2f(v & 0xffffu);
    s1 += bfu2f(v >> 16);
  }
  float inv = 1.0f / (float)max(end - beg, 1);
  unsigned o = f2bfu(s0 * inv) | (f2bfu(s1 * inv) << 16);
  *(unsigned*)(ABb + (size_t)node * 512 + lane * 4) = o;
}

// ---------------- GEMM1: H = relu(AB @ W1cat + b1), bf16 MFMA ----------------
// block: 256 thr = 4 waves; tile M=64, N=256 (wave w -> cols w*64..+63)
__global__ __launch_bounds__(256) void k_gemm1(
    const char* __restrict__ ABb, const short* __restrict__ Wt1,
    const float* __restrict__ b1, unsigned short* __restrict__ H) {
  __shared__ __align__(16) char As[64 * 512];
  const int tid = threadIdx.x;
  const int w = tid >> 6, lane = tid & 63;
  const int row0 = blockIdx.x * 64;

  {  // stage 64x256 bf16, swizzled source -> linear LDS dest
    const char* gbase = ABb + (size_t)row0 * 512;
#pragma unroll
    for (int i = 0; i < 8; ++i) {
      int o = i * 4096 + w * 1024 + lane * 16;
      int row = o >> 9;
      int kslot = ((o & 511) >> 4) ^ (row & 7);
      GLOAD_LDS16(gbase + row * 512 + kslot * 16, As + i * 4096 + w * 1024);
    }
  }
  __syncthreads();

  f32x4 acc[4][4];
#pragma unroll
  for (int mi = 0; mi < 4; ++mi)
#pragma unroll
    for (int ni = 0; ni < 4; ++ni) acc[mi][ni] = (f32x4){0.f, 0.f, 0.f, 0.f};

  const short* wb = Wt1 + (size_t)(w * 64 + (lane & 15)) * 256 + (lane >> 4) * 8;

  for (int ks = 0; ks < 8; ++ks) {
    short8 af[4], bf[4];
#pragma unroll
    for (int mi = 0; mi < 4; ++mi) {
      int row = mi * 16 + (lane & 15);
      int kslot = (ks * 4 + (lane >> 4)) ^ (row & 7);
      af[mi] = *(const short8*)(As + row * 512 + kslot * 16);
    }
#pragma unroll
    for (int ni = 0; ni < 4; ++ni)
      bf[ni] = *(const short8*)(wb + ni * 16 * 256 + ks * 32);
#pragma unroll
    for (int mi = 0; mi < 4; ++mi)
#pragma unroll
      for (int ni = 0; ni < 4; ++ni)
        acc[mi][ni] = __builtin_amdgcn_mfma_f32_16x16x32_bf16(
            af[mi], bf[ni], acc[mi][ni], 0, 0, 0);
  }

#pragma unroll
  for (int ni = 0; ni < 4; ++ni) {
    int col = w * 64 + ni * 16 + (lane & 15);
    float bv = b1[col];
#pragma unroll
    for (int mi = 0; mi < 4; ++mi) {
      int rbase = row0 + mi * 16 + (lane >> 4) * 4;
#pragma unroll
      for (int r = 0; r < 4; ++r) {
        float v = fmaxf(acc[mi][ni][r] + bv, 0.f);
        H[(size_t)(rbase + r) * 256 + col] = (unsigned short)f2bfu(v);
      }
    }
  }
}

// ---------------- GEMM2: [p2|r2] = H @ W2cat (+b2 on r2), bf16 MFMA ----------
// block: 4 waves; wave w -> rows w*16..+15, all 80 cols
__global__ __launch_bounds__(256) void k_gemm2(
    const char* __restrict__ Hb, const short* __restrict__ Wt2,
    const float* __restrict__ b2, unsigned short* __restrict__ P2,
    float* __restrict__ R2) {
  __shared__ __align__(16) char As[64 * 512];
  const int tid = threadIdx.x;
  const int w = tid >> 6, lane = tid & 63;
  const int row0 = blockIdx.x * 64;

  {
    const char* gbase = Hb + (size_t)row0 * 512;
#pragma unroll
    for (int i = 0; i < 8; ++i) {
      int o = i * 4096 + w * 1024 + lane * 16;
      int row = o >> 9;
      int kslot = ((o & 511) >> 4) ^ (row & 7);
      GLOAD_LDS16(gbase + row * 512 + kslot * 16, As + i * 4096 + w * 1024);
    }
  }
  __syncthreads();

  f32x4 acc[5];
#pragma unroll
  for (int ni = 0; ni < 5; ++ni) acc[ni] = (f32x4){0.f, 0.f, 0.f, 0.f};

  const short* wb = Wt2 + (size_t)(lane & 15) * 256 + (lane >> 4) * 8;
  const int arow = w * 16 + (lane & 15);

  for (int ks = 0; ks < 8; ++ks) {
    int kslot = (ks * 4 + (lane >> 4)) ^ (arow & 7);
    short8 a = *(const short8*)(As + arow * 512 + kslot * 16);
#pragma unroll
    for (int ni = 0; ni < 5; ++ni) {
      short8 bf = *(const short8*)(wb + ni * 16 * 256 + ks * 32);
      acc[ni] = __builtin_amdgcn_mfma_f32_16x16x32_bf16(a, bf, acc[ni], 0, 0, 0);
    }
  }

#pragma unroll
  for (int ni = 0; ni < 5; ++ni) {
    int col = ni * 16 + (lane & 15);
#pragma unroll
    for (int r = 0; r < 4; ++r) {
      int row = row0 + w * 16 + (lane >> 4) * 4 + r;
      float v = acc[ni][r];
      if (col < OUT_DIM) {
        P2[(size_t)row * OUT_DIM + col] = (unsigned short)f2bfu(v);
      } else {
        R2[(size_t)row * OUT_DIM + (col - OUT_DIM)] = v + b2[col - OUT_DIM];
      }
    }
  }
}

// ---------------- agg2 + log_softmax ----------------
__global__ __launch_bounds__(256) void k_agg2(const unsigned short* __restrict__ P2,
    const float* __restrict__ R2, const int* __restrict__ row_ptr,
    const int* __restrict__ esrc, float* __restrict__ out) {
  int tid = threadIdx.x;
  int node = blockIdx.x * 4 + (tid >> 6);
  int lane = tid & 63;
  int beg = row_ptr[node], end = row_ptr[node + 1];
  float acc = 0.f;
  if (lane < OUT_DIM) {
    for (int e = beg; e < end; ++e)
      acc += bfu2f(P2[(size_t)esrc[e] * OUT_DIM + lane]);
  }
  float inv = 1.0f / (float)max(end - beg, 1);
  float v = (lane < OUT_DIM)
                ? acc * inv + R2[(size_t)node * OUT_DIM + lane]
                : -1e30f;
  float m = v;
#pragma unroll
  for (int o = 32; o; o >>= 1) m = fmaxf(m, __shfl_xor(m, o, 64));
  float ex = (lane < OUT_DIM) ? __expf(v - m) : 0.f;
  float ssum = ex;
#pragma unroll
  for (int o = 32; o; o >>= 1) ssum += __shfl_xor(ssum, o, 64);
  float ls = __logf(ssum) + m;
  if (lane < OUT_DIM) out[(size_t)node * OUT_DIM + lane] = v - ls;
}

extern "C" void kernel_launch(void* const* d_in, const int* in_sizes, int n_in,
                              void* d_out, int out_size, void* d_ws, size_t ws_size,
                              hipStream_t stream) {
  const float* x   = (const float*)d_in[0];
  const int*   ei  = (const int*)d_in[1];
  const float* W1l = (const float*)d_in[2];
  const float* W1r = (const float*)d_in[3];
  const float* b1  = (const float*)d_in[4];
  const float* W2l = (const float*)d_in[5];
  const float* W2r = (const float*)d_in[6];
  const float* b2  = (const float*)d_in[7];
  float* out = (float*)d_out;

  const int* src = ei;
  const int* dst = ei + N_EDGES;

  char* ws = (char*)d_ws;
  int*   cnt     = (int*)(ws + OFF_CNT);
  int*   row_ptr = (int*)(ws + OFF_RP);
  int*   cursor  = (int*)(ws + OFF_CUR);
  int*   esrc    = (int*)(ws + OFF_ESRC);
  char*  ABb     = ws + OFF_AB;
  char*  Hb      = ws + OFF_H;
  unsigned short* Wt1 = (unsigned short*)(ws + OFF_W1T);
  unsigned short* Wt2 = (unsigned short*)(ws + OFF_W2T);
  unsigned short* P2  = (unsigned short*)(ws + OFF_P2);
  float* R2 = (float*)(ws + OFF_R2);

  (void)hipMemsetAsync(cnt, 0, N_NODES * sizeof(int), stream);
  (void)hipMemsetAsync(ABb + (size_t)N_NODES * 512, 0, (M_PAD - N_NODES) * 512,
                       stream);

  k_convx<<<(N_NODES * 16 + 255) / 256, 256, 0, stream>>>(x, ABb);
  k_convw1<<<256, 256, 0, stream>>>(W1l, W1r, Wt1);
  k_convw2<<<80, 256, 0, stream>>>(W2l, W2r, Wt2);

  k_count<<<(N_EDGES + 255) / 256, 256, 0, stream>>>(dst, cnt);
  k_scan<<<1, 1024, 0, stream>>>(cnt, row_ptr, cursor);
  k_fill<<<(N_EDGES + 255) / 256, 256, 0, stream>>>(src, dst, cursor, esrc);

  k_agg1<<<N_NODES / 4, 256, 0, stream>>>(ABb, row_ptr, esrc);
  k_gemm1<<<M_PAD / 64, 256, 0, stream>>>(ABb, (const short*)Wt1, b1,
                                          (unsigned short*)Hb);
  k_gemm2<<<M_PAD / 64, 256, 0, stream>>>(Hb, (const short*)Wt2, b2, P2, R2);
  k_agg2<<<N_NODES / 4, 256, 0, stream>>>(P2, R2, row_ptr, esrc, out);
}

// Round 5
// 376.068 us; speedup vs baseline: 5.8614x; 1.2677x over previous
//
#include <hip/hip_runtime.h>
#include <hip/hip_bf16.h>

#define N_NODES 50000
#define N_EDGES 800000
#define IN_DIM 128
#define HID_DIM 256
#define OUT_DIM 40
#define M_PAD 50048   // 782 * 64
#define SCAN_BLOCKS 196  // 196*256 = 50176 >= 50000

// ---- workspace layout (bytes), all 16-B aligned ----
#define OFF_CNT   0          // 50000 int
#define OFF_RP    200192     // 50001 int row_ptr
#define OFF_CUR   400640     // 50001 int cursor
#define OFF_ESRC  601088     // 800000 int
#define OFF_AB    3801088    // M_PAD x 256 bf16 (cols 0-127 agg1, 128-255 x) 25.6MB
#define OFF_H     29425664   // M_PAD x 256 bf16
#define OFF_W1T   55050240   // 256 x 256 bf16 (Wt1[n][k])
#define OFF_W2T   55181312   // 80 x 256 bf16
#define OFF_P2    55222272   // M_PAD x 40 bf16
#define OFF_R2    59226112   // M_PAD x 40 f32
#define OFF_BSUM  67233792   // 256 int
#define OFF_BOFF  67234816   // 256 int
// end 67235840

typedef __attribute__((ext_vector_type(8))) short short8;
typedef __attribute__((ext_vector_type(4))) float f32x4;

__device__ __forceinline__ float bfu2f(unsigned u) {
  union { unsigned i; float f; } c; c.i = u << 16; return c.f;
}
__device__ __forceinline__ unsigned f2bfu(float f) {
  union { float f; unsigned i; } c; c.f = f;
  return (c.i + 0x7fffu + ((c.i >> 16) & 1u)) >> 16;   // RNE
}

#define GLOAD_LDS16(g, l)                                                      \
  __builtin_amdgcn_global_load_lds(                                            \
      (const __attribute__((address_space(1))) void*)(g),                      \
      (__attribute__((address_space(3))) void*)(l), 16, 0, 0)

// ---------------- CSR build ----------------
__global__ void k_count(const int* __restrict__ dst, int* __restrict__ cnt) {
  int e = blockIdx.x * blockDim.x + threadIdx.x;
  if (e < N_EDGES) atomicAdd(&cnt[dst[e]], 1);
}

// phase A: per-block sum of 256 counts
__global__ __launch_bounds__(256) void k_scanA(const int* __restrict__ cnt,
                                               int* __restrict__ bsum) {
  __shared__ int red[256];
  int t = threadIdx.x;
  int node = blockIdx.x * 256 + t;
  red[t] = (node < N_NODES) ? cnt[node] : 0;
  __syncthreads();
  for (int off = 128; off; off >>= 1) {
    if (t < off) red[t] += red[t + off];
    __syncthreads();
  }
  if (t == 0) bsum[blockIdx.x] = red[0];
}

// phase B: single block scans 196 block sums -> exclusive offsets + total
__global__ __launch_bounds__(256) void k_scanB(const int* __restrict__ bsum,
                                               int* __restrict__ boff,
                                               int* __restrict__ row_ptr) {
  __shared__ int part[256];
  int t = threadIdx.x;
  int v = (t < SCAN_BLOCKS) ? bsum[t] : 0;
  part[t] = v;
  __syncthreads();
  for (int off = 1; off < 256; off <<= 1) {
    int u = (t >= off) ? part[t - off] : 0;
    __syncthreads();
    part[t] += u;
    __syncthreads();
  }
  if (t < SCAN_BLOCKS) boff[t] = part[t] - v;
  if (t == 255) row_ptr[N_NODES] = part[255];
}

// phase C: intra-block exclusive scan + block offset -> row_ptr, cursor
__global__ __launch_bounds__(256) void k_scanC(const int* __restrict__ cnt,
                                               const int* __restrict__ boff,
                                               int* __restrict__ row_ptr,
                                               int* __restrict__ cursor) {
  __shared__ int part[256];
  int t = threadIdx.x;
  int node = blockIdx.x * 256 + t;
  int v = (node < N_NODES) ? cnt[node] : 0;
  part[t] = v;
  __syncthreads();
  for (int off = 1; off < 256; off <<= 1) {
    int u = (t >= off) ? part[t - off] : 0;
    __syncthreads();
    part[t] += u;
    __syncthreads();
  }
  if (node < N_NODES) {
    int e = boff[blockIdx.x] + part[t] - v;
    row_ptr[node] = e;
    cursor[node] = e;
  }
}

__global__ void k_fill(const int* __restrict__ src, const int* __restrict__ dst,
                       int* __restrict__ cursor, int* __restrict__ esrc) {
  int e = blockIdx.x * blockDim.x + threadIdx.x;
  if (e >= N_EDGES) return;
  int p = atomicAdd(&cursor[dst[e]], 1);
  esrc[p] = src[e];
}

// ---------------- conversions ----------------
__global__ __launch_bounds__(256) void k_convx(const float* __restrict__ x,
                                               char* __restrict__ ABb) {
  int t = blockIdx.x * 256 + threadIdx.x;
  int row = t >> 4, c8 = (t & 15) << 3;
  if (row >= N_NODES) return;
  const float* xp = x + (size_t)row * IN_DIM + c8;
  unsigned short o[8];
#pragma unroll
  for (int i = 0; i < 8; ++i) o[i] = (unsigned short)f2bfu(xp[i]);
  *(short8*)(ABb + (size_t)row * 512 + 256 + c8 * 2) = *(short8*)o;
}

__global__ __launch_bounds__(256) void k_convw1(const float* __restrict__ W1l,
                                                const float* __restrict__ W1r,
                                                unsigned short* __restrict__ Wt1) {
  int n = blockIdx.x, k = threadIdx.x;
  float v = (k < 128) ? W1l[(size_t)k * HID_DIM + n]
                      : W1r[(size_t)(k - 128) * HID_DIM + n];
  Wt1[(size_t)n * 256 + k] = (unsigned short)f2bfu(v);
}

__global__ __launch_bounds__(256) void k_convw2(const float* __restrict__ W2l,
                                                const float* __restrict__ W2r,
                                                unsigned short* __restrict__ Wt2) {
  int n = blockIdx.x, k = threadIdx.x;
  float v = (n < OUT_DIM) ? W2l[(size_t)k * OUT_DIM + n]
                          : W2r[(size_t)k * OUT_DIM + (n - OUT_DIM)];
  Wt2[(size_t)n * 256 + k] = (unsigned short)f2bfu(v);
}

// ---------------- aggregation 1 (bf16 gather, mean) ----------------
__global__ __launch_bounds__(256) void k_agg1(char* __restrict__ ABb,
    const int* __restrict__ row_ptr, const int* __restrict__ esrc) {
  int tid = threadIdx.x;
  int node = blockIdx.x * 4 + (tid >> 6);
  int lane = tid & 63;
  int beg = row_ptr[node], end = row_ptr[node + 1];
  float s0 = 0.f, s1 = 0.f;
  for (int e = beg; e < end; ++e) {
    unsigned v = *(const unsigned*)(ABb + (size_t)esrc[e] * 512 + 256 + lane * 4);
    s0 += bfu2f(v & 0xffffu);
    s1 += bfu2f(v >> 16);
  }
  float inv = 1.0f / (float)max(end - beg, 1);
  unsigned o = f2bfu(s0 * inv) | (f2bfu(s1 * inv) << 16);
  *(unsigned*)(ABb + (size_t)node * 512 + lane * 4) = o;
}

// ---------------- GEMM1: H = relu(AB @ W1cat + b1), bf16 MFMA ----------------
__global__ __launch_bounds__(256) void k_gemm1(
    const char* __restrict__ ABb, const short* __restrict__ Wt1,
    const float* __restrict__ b1, unsigned short* __restrict__ H) {
  __shared__ __align__(16) char As[64 * 512];
  const int tid = threadIdx.x;
  const int w = tid >> 6, lane = tid & 63;
  const int row0 = blockIdx.x * 64;

  {
    const char* gbase = ABb + (size_t)row0 * 512;
#pragma unroll
    for (int i = 0; i < 8; ++i) {
      int o = i * 4096 + w * 1024 + lane * 16;
      int row = o >> 9;
      int kslot = ((o & 511) >> 4) ^ (row & 7);
      GLOAD_LDS16(gbase + row * 512 + kslot * 16, As + i * 4096 + w * 1024);
    }
  }
  __syncthreads();

  f32x4 acc[4][4];
#pragma unroll
  for (int mi = 0; mi < 4; ++mi)
#pragma unroll
    for (int ni = 0; ni < 4; ++ni) acc[mi][ni] = (f32x4){0.f, 0.f, 0.f, 0.f};

  const short* wb = Wt1 + (size_t)(w * 64 + (lane & 15)) * 256 + (lane >> 4) * 8;

  for (int ks = 0; ks < 8; ++ks) {
    short8 af[4], bf[4];
#pragma unroll
    for (int mi = 0; mi < 4; ++mi) {
      int row = mi * 16 + (lane & 15);
      int kslot = (ks * 4 + (lane >> 4)) ^ (row & 7);
      af[mi] = *(const short8*)(As + row * 512 + kslot * 16);
    }
#pragma unroll
    for (int ni = 0; ni < 4; ++ni)
      bf[ni] = *(const short8*)(wb + ni * 16 * 256 + ks * 32);
#pragma unroll
    for (int mi = 0; mi < 4; ++mi)
#pragma unroll
      for (int ni = 0; ni < 4; ++ni)
        acc[mi][ni] = __builtin_amdgcn_mfma_f32_16x16x32_bf16(
            af[mi], bf[ni], acc[mi][ni], 0, 0, 0);
  }

#pragma unroll
  for (int ni = 0; ni < 4; ++ni) {
    int col = w * 64 + ni * 16 + (lane & 15);
    float bv = b1[col];
#pragma unroll
    for (int mi = 0; mi < 4; ++mi) {
      int rbase = row0 + mi * 16 + (lane >> 4) * 4;
#pragma unroll
      for (int r = 0; r < 4; ++r) {
        float v = fmaxf(acc[mi][ni][r] + bv, 0.f);
        H[(size_t)(rbase + r) * 256 + col] = (unsigned short)f2bfu(v);
      }
    }
  }
}

// ---------------- GEMM2: [p2|r2] = H @ W2cat (+b2 on r2), bf16 MFMA ----------
__global__ __launch_bounds__(256) void k_gemm2(
    const char* __restrict__ Hb, const short* __restrict__ Wt2,
    const float* __restrict__ b2, unsigned short* __restrict__ P2,
    float* __restrict__ R2) {
  __shared__ __align__(16) char As[64 * 512];
  const int tid = threadIdx.x;
  const int w = tid >> 6, lane = tid & 63;
  const int row0 = blockIdx.x * 64;

  {
    const char* gbase = Hb + (size_t)row0 * 512;
#pragma unroll
    for (int i = 0; i < 8; ++i) {
      int o = i * 4096 + w * 1024 + lane * 16;
      int row = o >> 9;
      int kslot = ((o & 511) >> 4) ^ (row & 7);
      GLOAD_LDS16(gbase + row * 512 + kslot * 16, As + i * 4096 + w * 1024);
    }
  }
  __syncthreads();

  f32x4 acc[5];
#pragma unroll
  for (int ni = 0; ni < 5; ++ni) acc[ni] = (f32x4){0.f, 0.f, 0.f, 0.f};

  const short* wb = Wt2 + (size_t)(lane & 15) * 256 + (lane >> 4) * 8;
  const int arow = w * 16 + (lane & 15);

  for (int ks = 0; ks < 8; ++ks) {
    int kslot = (ks * 4 + (lane >> 4)) ^ (arow & 7);
    short8 a = *(const short8*)(As + arow * 512 + kslot * 16);
#pragma unroll
    for (int ni = 0; ni < 5; ++ni) {
      short8 bf = *(const short8*)(wb + ni * 16 * 256 + ks * 32);
      acc[ni] = __builtin_amdgcn_mfma_f32_16x16x32_bf16(a, bf, acc[ni], 0, 0, 0);
    }
  }

#pragma unroll
  for (int ni = 0; ni < 5; ++ni) {
    int col = ni * 16 + (lane & 15);
#pragma unroll
    for (int r = 0; r < 4; ++r) {
      int row = row0 + w * 16 + (lane >> 4) * 4 + r;
      float v = acc[ni][r];
      if (col < OUT_DIM) {
        P2[(size_t)row * OUT_DIM + col] = (unsigned short)f2bfu(v);
      } else {
        R2[(size_t)row * OUT_DIM + (col - OUT_DIM)] = v + b2[col - OUT_DIM];
      }
    }
  }
}

// ---------------- agg2 + log_softmax ----------------
__global__ __launch_bounds__(256) void k_agg2(const unsigned short* __restrict__ P2,
    const float* __restrict__ R2, const int* __restrict__ row_ptr,
    const int* __restrict__ esrc, float* __restrict__ out) {
  int tid = threadIdx.x;
  int node = blockIdx.x * 4 + (tid >> 6);
  int lane = tid & 63;
  int beg = row_ptr[node], end = row_ptr[node + 1];
  float acc = 0.f;
  if (lane < OUT_DIM) {
    for (int e = beg; e < end; ++e)
      acc += bfu2f(P2[(size_t)esrc[e] * OUT_DIM + lane]);
  }
  float inv = 1.0f / (float)max(end - beg, 1);
  float v = (lane < OUT_DIM)
                ? acc * inv + R2[(size_t)node * OUT_DIM + lane]
                : -1e30f;
  float m = v;
#pragma unroll
  for (int o = 32; o; o >>= 1) m = fmaxf(m, __shfl_xor(m, o, 64));
  float ex = (lane < OUT_DIM) ? __expf(v - m) : 0.f;
  float ssum = ex;
#pragma unroll
  for (int o = 32; o; o >>= 1) ssum += __shfl_xor(ssum, o, 64);
  float ls = __logf(ssum) + m;
  if (lane < OUT_DIM) out[(size_t)node * OUT_DIM + lane] = v - ls;
}

extern "C" void kernel_launch(void* const* d_in, const int* in_sizes, int n_in,
                              void* d_out, int out_size, void* d_ws, size_t ws_size,
                              hipStream_t stream) {
  const float* x   = (const float*)d_in[0];
  const int*   ei  = (const int*)d_in[1];
  const float* W1l = (const float*)d_in[2];
  const float* W1r = (const float*)d_in[3];
  const float* b1  = (const float*)d_in[4];
  const float* W2l = (const float*)d_in[5];
  const float* W2r = (const float*)d_in[6];
  const float* b2  = (const float*)d_in[7];
  float* out = (float*)d_out;

  const int* src = ei;
  const int* dst = ei + N_EDGES;

  char* ws = (char*)d_ws;
  int*   cnt     = (int*)(ws + OFF_CNT);
  int*   row_ptr = (int*)(ws + OFF_RP);
  int*   cursor  = (int*)(ws + OFF_CUR);
  int*   esrc    = (int*)(ws + OFF_ESRC);
  char*  ABb     = ws + OFF_AB;
  char*  Hb      = ws + OFF_H;
  unsigned short* Wt1 = (unsigned short*)(ws + OFF_W1T);
  unsigned short* Wt2 = (unsigned short*)(ws + OFF_W2T);
  unsigned short* P2  = (unsigned short*)(ws + OFF_P2);
  float* R2   = (float*)(ws + OFF_R2);
  int*   bsum = (int*)(ws + OFF_BSUM);
  int*   boff = (int*)(ws + OFF_BOFF);

  (void)hipMemsetAsync(cnt, 0, N_NODES * sizeof(int), stream);
  (void)hipMemsetAsync(ABb + (size_t)N_NODES * 512, 0, (M_PAD - N_NODES) * 512,
                       stream);

  k_convx<<<(N_NODES * 16 + 255) / 256, 256, 0, stream>>>(x, ABb);
  k_convw1<<<256, 256, 0, stream>>>(W1l, W1r, Wt1);
  k_convw2<<<80, 256, 0, stream>>>(W2l, W2r, Wt2);

  k_count<<<(N_EDGES + 255) / 256, 256, 0, stream>>>(dst, cnt);
  k_scanA<<<SCAN_BLOCKS, 256, 0, stream>>>(cnt, bsum);
  k_scanB<<<1, 256, 0, stream>>>(bsum, boff, row_ptr);
  k_scanC<<<SCAN_BLOCKS, 256, 0, stream>>>(cnt, boff, row_ptr, cursor);
  k_fill<<<(N_EDGES + 255) / 256, 256, 0, stream>>>(src, dst, cursor, esrc);

  k_agg1<<<N_NODES / 4, 256, 0, stream>>>(ABb, row_ptr, esrc);
  k_gemm1<<<M_PAD / 64, 256, 0, stream>>>(ABb, (const short*)Wt1, b1,
                                          (unsigned short*)Hb);
  k_gemm2<<<M_PAD / 64, 256, 0, stream>>>(Hb, (const short*)Wt2, b2, P2, R2);
  k_agg2<<<N_NODES / 4, 256, 0, stream>>>(P2, R2, row_ptr, esrc, out);
}

// Round 6
// 314.567 us; speedup vs baseline: 7.0074x; 1.1955x over previous
//
#include <hip/hip_runtime.h>
#include <hip/hip_bf16.h>

#define N_NODES 50000
#define N_EDGES 800000
#define IN_DIM 128
#define HID_DIM 256
#define OUT_DIM 40
#define M_PAD 50048   // 782 * 64
#define SCAN_BLOCKS 196  // 196*256 = 50176 >= 50000

// ---- workspace layout (bytes), all 16-B aligned ----
#define OFF_CNT   0          // 50000 int
#define OFF_RP    200192     // 50001 int row_ptr
#define OFF_CUR   400640     // 50001 int cursor
#define OFF_ESRC  601088     // 800000 int
#define OFF_AB    3801088    // M_PAD x 256 bf16 (cols 0-127 agg1, 128-255 x) 25.6MB
#define OFF_H     29425664   // M_PAD x 256 bf16
#define OFF_W1T   55050240   // 256 x 256 bf16 (Wt1[n][k])
#define OFF_W2T   55181312   // 80 x 256 bf16
#define OFF_P2    55222272   // M_PAD x 40 bf16
#define OFF_R2    59226112   // M_PAD x 40 f32
#define OFF_BSUM  67233792   // 256 int
#define OFF_BOFF  67234816   // 256 int
// end 67235840

typedef __attribute__((ext_vector_type(8))) short short8;
typedef __attribute__((ext_vector_type(4))) float f32x4;

__device__ __forceinline__ float bfu2f(unsigned u) {
  union { unsigned i; float f; } c; c.i = u << 16; return c.f;
}
__device__ __forceinline__ unsigned f2bfu(float f) {
  union { float f; unsigned i; } c; c.f = f;
  return (c.i + 0x7fffu + ((c.i >> 16) & 1u)) >> 16;   // RNE
}

#define GLOAD_LDS16(g, l)                                                      \
  __builtin_amdgcn_global_load_lds(                                            \
      (const __attribute__((address_space(1))) void*)(g),                      \
      (__attribute__((address_space(3))) void*)(l), 16, 0, 0)

// ---------------- CSR build ----------------
__global__ void k_count(const int* __restrict__ dst, int* __restrict__ cnt) {
  int e = blockIdx.x * blockDim.x + threadIdx.x;
  if (e < N_EDGES) atomicAdd(&cnt[dst[e]], 1);
}

__global__ __launch_bounds__(256) void k_scanA(const int* __restrict__ cnt,
                                               int* __restrict__ bsum) {
  __shared__ int red[256];
  int t = threadIdx.x;
  int node = blockIdx.x * 256 + t;
  red[t] = (node < N_NODES) ? cnt[node] : 0;
  __syncthreads();
  for (int off = 128; off; off >>= 1) {
    if (t < off) red[t] += red[t + off];
    __syncthreads();
  }
  if (t == 0) bsum[blockIdx.x] = red[0];
}

__global__ __launch_bounds__(256) void k_scanB(const int* __restrict__ bsum,
                                               int* __restrict__ boff,
                                               int* __restrict__ row_ptr) {
  __shared__ int part[256];
  int t = threadIdx.x;
  int v = (t < SCAN_BLOCKS) ? bsum[t] : 0;
  part[t] = v;
  __syncthreads();
  for (int off = 1; off < 256; off <<= 1) {
    int u = (t >= off) ? part[t - off] : 0;
    __syncthreads();
    part[t] += u;
    __syncthreads();
  }
  if (t < SCAN_BLOCKS) boff[t] = part[t] - v;
  if (t == 255) row_ptr[N_NODES] = part[255];
}

__global__ __launch_bounds__(256) void k_scanC(const int* __restrict__ cnt,
                                               const int* __restrict__ boff,
                                               int* __restrict__ row_ptr,
                                               int* __restrict__ cursor) {
  __shared__ int part[256];
  int t = threadIdx.x;
  int node = blockIdx.x * 256 + t;
  int v = (node < N_NODES) ? cnt[node] : 0;
  part[t] = v;
  __syncthreads();
  for (int off = 1; off < 256; off <<= 1) {
    int u = (t >= off) ? part[t - off] : 0;
    __syncthreads();
    part[t] += u;
    __syncthreads();
  }
  if (node < N_NODES) {
    int e = boff[blockIdx.x] + part[t] - v;
    row_ptr[node] = e;
    cursor[node] = e;
  }
}

__global__ void k_fill(const int* __restrict__ src, const int* __restrict__ dst,
                       int* __restrict__ cursor, int* __restrict__ esrc) {
  int e = blockIdx.x * blockDim.x + threadIdx.x;
  if (e >= N_EDGES) return;
  int p = atomicAdd(&cursor[dst[e]], 1);
  esrc[p] = src[e];
}

// ---------------- conversions ----------------
__global__ __launch_bounds__(256) void k_convx(const float* __restrict__ x,
                                               char* __restrict__ ABb) {
  int t = blockIdx.x * 256 + threadIdx.x;
  int row = t >> 4, c8 = (t & 15) << 3;
  if (row >= N_NODES) return;
  const float* xp = x + (size_t)row * IN_DIM + c8;
  unsigned short o[8];
#pragma unroll
  for (int i = 0; i < 8; ++i) o[i] = (unsigned short)f2bfu(xp[i]);
  *(short8*)(ABb + (size_t)row * 512 + 256 + c8 * 2) = *(short8*)o;
}

__global__ __launch_bounds__(256) void k_convw1(const float* __restrict__ W1l,
                                                const float* __restrict__ W1r,
                                                unsigned short* __restrict__ Wt1) {
  int n = blockIdx.x, k = threadIdx.x;
  float v = (k < 128) ? W1l[(size_t)k * HID_DIM + n]
                      : W1r[(size_t)(k - 128) * HID_DIM + n];
  Wt1[(size_t)n * 256 + k] = (unsigned short)f2bfu(v);
}

__global__ __launch_bounds__(256) void k_convw2(const float* __restrict__ W2l,
                                                const float* __restrict__ W2r,
                                                unsigned short* __restrict__ Wt2) {
  int n = blockIdx.x, k = threadIdx.x;
  float v = (n < OUT_DIM) ? W2l[(size_t)k * OUT_DIM + n]
                          : W2r[(size_t)k * OUT_DIM + (n - OUT_DIM)];
  Wt2[(size_t)n * 256 + k] = (unsigned short)f2bfu(v);
}

// ---------------- aggregation 1 (bf16 gather, mean) ----------------
// wave per node; 4 edges per iteration: 16-lane group g handles edge e0+g,
// lane q (0..15) in group loads 8 channels (16B). Cross-group shfl reduce.
__global__ __launch_bounds__(256) void k_agg1(char* __restrict__ ABb,
    const int* __restrict__ row_ptr, const int* __restrict__ esrc) {
  int tid = threadIdx.x;
  int node = blockIdx.x * 4 + (tid >> 6);
  int lane = tid & 63;
  int g = lane >> 4;        // 0..3 edge subgroup
  int q = lane & 15;        // channel slot: ch q*8..q*8+7
  int beg = row_ptr[node], end = row_ptr[node + 1];
  float s[8];
#pragma unroll
  for (int j = 0; j < 8; ++j) s[j] = 0.f;

  for (int e0 = beg; e0 < end; e0 += 4) {
    int e = e0 + g;
    if (e < end) {
      int srcn = esrc[e];
      short8 v = *(const short8*)(ABb + (size_t)srcn * 512 + 256 + q * 16);
#pragma unroll
      for (int j = 0; j < 8; ++j)
        s[j] += bfu2f((unsigned short)v[j]);
    }
  }
  // sum across the 4 groups (lanes with equal q share channels)
#pragma unroll
  for (int j = 0; j < 8; ++j) {
    s[j] += __shfl_xor(s[j], 16, 64);
    s[j] += __shfl_xor(s[j], 32, 64);
  }
  float inv = 1.0f / (float)max(end - beg, 1);
  if (lane < 16) {
    unsigned short o[8];
#pragma unroll
    for (int j = 0; j < 8; ++j) o[j] = (unsigned short)f2bfu(s[j] * inv);
    *(short8*)(ABb + (size_t)node * 512 + q * 16) = *(short8*)o;
  }
}

// ---------------- GEMM1: H = relu(AB @ W1cat + b1), bf16 MFMA ----------------
__global__ __launch_bounds__(256) void k_gemm1(
    const char* __restrict__ ABb, const short* __restrict__ Wt1,
    const float* __restrict__ b1, unsigned short* __restrict__ H) {
  __shared__ __align__(16) char As[64 * 512];
  const int tid = threadIdx.x;
  const int w = tid >> 6, lane = tid & 63;
  const int row0 = blockIdx.x * 64;

  {
    const char* gbase = ABb + (size_t)row0 * 512;
#pragma unroll
    for (int i = 0; i < 8; ++i) {
      int o = i * 4096 + w * 1024 + lane * 16;
      int row = o >> 9;
      int kslot = ((o & 511) >> 4) ^ (row & 7);
      GLOAD_LDS16(gbase + row * 512 + kslot * 16, As + i * 4096 + w * 1024);
    }
  }
  __syncthreads();

  f32x4 acc[4][4];
#pragma unroll
  for (int mi = 0; mi < 4; ++mi)
#pragma unroll
    for (int ni = 0; ni < 4; ++ni) acc[mi][ni] = (f32x4){0.f, 0.f, 0.f, 0.f};

  const short* wb = Wt1 + (size_t)(w * 64 + (lane & 15)) * 256 + (lane >> 4) * 8;

  for (int ks = 0; ks < 8; ++ks) {
    short8 af[4], bf[4];
#pragma unroll
    for (int mi = 0; mi < 4; ++mi) {
      int row = mi * 16 + (lane & 15);
      int kslot = (ks * 4 + (lane >> 4)) ^ (row & 7);
      af[mi] = *(const short8*)(As + row * 512 + kslot * 16);
    }
#pragma unroll
    for (int ni = 0; ni < 4; ++ni)
      bf[ni] = *(const short8*)(wb + ni * 16 * 256 + ks * 32);
#pragma unroll
    for (int mi = 0; mi < 4; ++mi)
#pragma unroll
      for (int ni = 0; ni < 4; ++ni)
        acc[mi][ni] = __builtin_amdgcn_mfma_f32_16x16x32_bf16(
            af[mi], bf[ni], acc[mi][ni], 0, 0, 0);
  }

#pragma unroll
  for (int ni = 0; ni < 4; ++ni) {
    int col = w * 64 + ni * 16 + (lane & 15);
    float bv = b1[col];
#pragma unroll
    for (int mi = 0; mi < 4; ++mi) {
      int rbase = row0 + mi * 16 + (lane >> 4) * 4;
#pragma unroll
      for (int r = 0; r < 4; ++r) {
        float v = fmaxf(acc[mi][ni][r] + bv, 0.f);
        H[(size_t)(rbase + r) * 256 + col] = (unsigned short)f2bfu(v);
      }
    }
  }
}

// ---------------- GEMM2: [p2|r2] = H @ W2cat (+b2 on r2), bf16 MFMA ----------
__global__ __launch_bounds__(256) void k_gemm2(
    const char* __restrict__ Hb, const short* __restrict__ Wt2,
    const float* __restrict__ b2, unsigned short* __restrict__ P2,
    float* __restrict__ R2) {
  __shared__ __align__(16) char As[64 * 512];
  const int tid = threadIdx.x;
  const int w = tid >> 6, lane = tid & 63;
  const int row0 = blockIdx.x * 64;

  {
    const char* gbase = Hb + (size_t)row0 * 512;
#pragma unroll
    for (int i = 0; i < 8; ++i) {
      int o = i * 4096 + w * 1024 + lane * 16;
      int row = o >> 9;
      int kslot = ((o & 511) >> 4) ^ (row & 7);
      GLOAD_LDS16(gbase + row * 512 + kslot * 16, As + i * 4096 + w * 1024);
    }
  }
  __syncthreads();

  f32x4 acc[5];
#pragma unroll
  for (int ni = 0; ni < 5; ++ni) acc[ni] = (f32x4){0.f, 0.f, 0.f, 0.f};

  const short* wb = Wt2 + (size_t)(lane & 15) * 256 + (lane >> 4) * 8;
  const int arow = w * 16 + (lane & 15);

  for (int ks = 0; ks < 8; ++ks) {
    int kslot = (ks * 4 + (lane >> 4)) ^ (arow & 7);
    short8 a = *(const short8*)(As + arow * 512 + kslot * 16);
#pragma unroll
    for (int ni = 0; ni < 5; ++ni) {
      short8 bf = *(const short8*)(wb + ni * 16 * 256 + ks * 32);
      acc[ni] = __builtin_amdgcn_mfma_f32_16x16x32_bf16(a, bf, acc[ni], 0, 0, 0);
    }
  }

#pragma unroll
  for (int ni = 0; ni < 5; ++ni) {
    int col = ni * 16 + (lane & 15);
#pragma unroll
    for (int r = 0; r < 4; ++r) {
      int row = row0 + w * 16 + (lane >> 4) * 4 + r;
      float v = acc[ni][r];
      if (col < OUT_DIM) {
        P2[(size_t)row * OUT_DIM + col] = (unsigned short)f2bfu(v);
      } else {
        R2[(size_t)row * OUT_DIM + (col - OUT_DIM)] = v + b2[col - OUT_DIM];
      }
    }
  }
}

// ---------------- agg2 + log_softmax ----------------
// wave per node; 2 edges per iteration (32-lane halves), lane q<20 loads
// 2 channels (u32). Cross-half shfl reduce, softmax within half.
__global__ __launch_bounds__(256) void k_agg2(const unsigned short* __restrict__ P2,
    const float* __restrict__ R2, const int* __restrict__ row_ptr,
    const int* __restrict__ esrc, float* __restrict__ out) {
  int tid = threadIdx.x;
  int node = blockIdx.x * 4 + (tid >> 6);
  int lane = tid & 63;
  int h = lane >> 5;        // half -> edge offset
  int q = lane & 31;        // 0..19 active, channels q*2, q*2+1
  int beg = row_ptr[node], end = row_ptr[node + 1];
  float s0 = 0.f, s1 = 0.f;
  if (q < 20) {
    for (int e0 = beg; e0 < end; e0 += 2) {
      int e = e0 + h;
      if (e < end) {
        unsigned v = *(const unsigned*)((const char*)P2 + (size_t)esrc[e] * 80 + q * 4);
        s0 += bfu2f(v & 0xffffu);
        s1 += bfu2f(v >> 16);
      }
    }
  }
  s0 += __shfl_xor(s0, 32, 64);
  s1 += __shfl_xor(s1, 32, 64);
  float inv = 1.0f / (float)max(end - beg, 1);
  float v0 = -1e30f, v1 = -1e30f;
  if (q < 20) {
    float2 r = *(const float2*)(R2 + (size_t)node * OUT_DIM + q * 2);
    v0 = s0 * inv + r.x;
    v1 = s1 * inv + r.y;
  }
  float m = fmaxf(v0, v1);
#pragma unroll
  for (int o = 16; o; o >>= 1) m = fmaxf(m, __shfl_xor(m, o, 64));
  float ex = (q < 20) ? __expf(v0 - m) + __expf(v1 - m) : 0.f;
  float ssum = ex;
#pragma unroll
  for (int o = 16; o; o >>= 1) ssum += __shfl_xor(ssum, o, 64);
  float ls = __logf(ssum) + m;
  if (h == 0 && q < 20) {
    float2 w = make_float2(v0 - ls, v1 - ls);
    *(float2*)(out + (size_t)node * OUT_DIM + q * 2) = w;
  }
}

extern "C" void kernel_launch(void* const* d_in, const int* in_sizes, int n_in,
                              void* d_out, int out_size, void* d_ws, size_t ws_size,
                              hipStream_t stream) {
  const float* x   = (const float*)d_in[0];
  const int*   ei  = (const int*)d_in[1];
  const float* W1l = (const float*)d_in[2];
  const float* W1r = (const float*)d_in[3];
  const float* b1  = (const float*)d_in[4];
  const float* W2l = (const float*)d_in[5];
  const float* W2r = (const float*)d_in[6];
  const float* b2  = (const float*)d_in[7];
  float* out = (float*)d_out;

  const int* src = ei;
  const int* dst = ei + N_EDGES;

  char* ws = (char*)d_ws;
  int*   cnt     = (int*)(ws + OFF_CNT);
  int*   row_ptr = (int*)(ws + OFF_RP);
  int*   cursor  = (int*)(ws + OFF_CUR);
  int*   esrc    = (int*)(ws + OFF_ESRC);
  char*  ABb     = ws + OFF_AB;
  char*  Hb      = ws + OFF_H;
  unsigned short* Wt1 = (unsigned short*)(ws + OFF_W1T);
  unsigned short* Wt2 = (unsigned short*)(ws + OFF_W2T);
  unsigned short* P2  = (unsigned short*)(ws + OFF_P2);
  float* R2   = (float*)(ws + OFF_R2);
  int*   bsum = (int*)(ws + OFF_BSUM);
  int*   boff = (int*)(ws + OFF_BOFF);

  (void)hipMemsetAsync(cnt, 0, N_NODES * sizeof(int), stream);
  (void)hipMemsetAsync(ABb + (size_t)N_NODES * 512, 0, (M_PAD - N_NODES) * 512,
                       stream);

  k_convx<<<(N_NODES * 16 + 255) / 256, 256, 0, stream>>>(x, ABb);
  k_convw1<<<256, 256, 0, stream>>>(W1l, W1r, Wt1);
  k_convw2<<<80, 256, 0, stream>>>(W2l, W2r, Wt2);

  k_count<<<(N_EDGES + 255) / 256, 256, 0, stream>>>(dst, cnt);
  k_scanA<<<SCAN_BLOCKS, 256, 0, stream>>>(cnt, bsum);
  k_scanB<<<1, 256, 0, stream>>>(bsum, boff, row_ptr);
  k_scanC<<<SCAN_BLOCKS, 256, 0, stream>>>(cnt, boff, row_ptr, cursor);
  k_fill<<<(N_EDGES + 255) / 256, 256, 0, stream>>>(src, dst, cursor, esrc);

  k_agg1<<<N_NODES / 4, 256, 0, stream>>>(ABb, row_ptr, esrc);
  k_gemm1<<<M_PAD / 64, 256, 0, stream>>>(ABb, (const short*)Wt1, b1,
                                          (unsigned short*)Hb);
  k_gemm2<<<M_PAD / 64, 256, 0, stream>>>(Hb, (const short*)Wt2, b2, P2, R2);
  k_agg2<<<N_NODES / 4, 256, 0, stream>>>(P2, R2, row_ptr, esrc, out);
}

// Round 7
// 296.912 us; speedup vs baseline: 7.4241x; 1.0595x over previous
//
#include <hip/hip_runtime.h>
#include <hip/hip_bf16.h>

#define N_NODES 50000
#define N_EDGES 800000
#define IN_DIM 128
#define HID_DIM 256
#define OUT_DIM 40
#define M_PAD 50048   // 782 * 64
#define SCAN_BLOCKS 196  // 196*256 = 50176 >= 50000

// ---- workspace layout (bytes), all 16-B aligned ----
#define OFF_CNT   0          // 50000 int
#define OFF_RP    200192     // 50001 int row_ptr
#define OFF_CUR   400640     // 50001 int cursor
#define OFF_ESRC  601088     // 800000 int
#define OFF_AB    3801088    // M_PAD x 256 bf16 (cols 0-127 agg1, 128-255 x) 25.6MB
#define OFF_H     29425664   // M_PAD x 256 bf16
#define OFF_W1T   55050240   // 256 x 256 bf16 (Wt1[n][k])
#define OFF_W2T   55181312   // 80 x 256 bf16
#define OFF_P2    55222272   // M_PAD x 40 bf16
#define OFF_R2    59226112   // M_PAD x 40 f32
#define OFF_BSUM  67233792   // 256 int
#define OFF_BOFF  67234816   // 256 int
// end 67235840

typedef __attribute__((ext_vector_type(8))) short short8;
typedef __attribute__((ext_vector_type(4))) float f32x4;

__device__ __forceinline__ float bfu2f(unsigned u) {
  union { unsigned i; float f; } c; c.i = u << 16; return c.f;
}
__device__ __forceinline__ unsigned f2bfu(float f) {
  union { float f; unsigned i; } c; c.f = f;
  return (c.i + 0x7fffu + ((c.i >> 16) & 1u)) >> 16;   // RNE
}

#define GLOAD_LDS16(g, l)                                                      \
  __builtin_amdgcn_global_load_lds(                                            \
      (const __attribute__((address_space(1))) void*)(g),                      \
      (__attribute__((address_space(3))) void*)(l), 16, 0, 0)

// ---------------- CSR build ----------------
__global__ void k_count(const int* __restrict__ dst, int* __restrict__ cnt) {
  int e = blockIdx.x * blockDim.x + threadIdx.x;
  if (e < N_EDGES) atomicAdd(&cnt[dst[e]], 1);
}

__global__ __launch_bounds__(256) void k_scanA(const int* __restrict__ cnt,
                                               int* __restrict__ bsum) {
  __shared__ int red[256];
  int t = threadIdx.x;
  int node = blockIdx.x * 256 + t;
  red[t] = (node < N_NODES) ? cnt[node] : 0;
  __syncthreads();
  for (int off = 128; off; off >>= 1) {
    if (t < off) red[t] += red[t + off];
    __syncthreads();
  }
  if (t == 0) bsum[blockIdx.x] = red[0];
}

__global__ __launch_bounds__(256) void k_scanB(const int* __restrict__ bsum,
                                               int* __restrict__ boff,
                                               int* __restrict__ row_ptr) {
  __shared__ int part[256];
  int t = threadIdx.x;
  int v = (t < SCAN_BLOCKS) ? bsum[t] : 0;
  part[t] = v;
  __syncthreads();
  for (int off = 1; off < 256; off <<= 1) {
    int u = (t >= off) ? part[t - off] : 0;
    __syncthreads();
    part[t] += u;
    __syncthreads();
  }
  if (t < SCAN_BLOCKS) boff[t] = part[t] - v;
  if (t == 255) row_ptr[N_NODES] = part[255];
}

__global__ __launch_bounds__(256) void k_scanC(const int* __restrict__ cnt,
                                               const int* __restrict__ boff,
                                               int* __restrict__ row_ptr,
                                               int* __restrict__ cursor) {
  __shared__ int part[256];
  int t = threadIdx.x;
  int node = blockIdx.x * 256 + t;
  int v = (node < N_NODES) ? cnt[node] : 0;
  part[t] = v;
  __syncthreads();
  for (int off = 1; off < 256; off <<= 1) {
    int u = (t >= off) ? part[t - off] : 0;
    __syncthreads();
    part[t] += u;
    __syncthreads();
  }
  if (node < N_NODES) {
    int e = boff[blockIdx.x] + part[t] - v;
    row_ptr[node] = e;
    cursor[node] = e;
  }
}

__global__ void k_fill(const int* __restrict__ src, const int* __restrict__ dst,
                       int* __restrict__ cursor, int* __restrict__ esrc) {
  int e = blockIdx.x * blockDim.x + threadIdx.x;
  if (e >= N_EDGES) return;
  int p = atomicAdd(&cursor[dst[e]], 1);
  esrc[p] = src[e];
}

// ---------------- conversions ----------------
__global__ __launch_bounds__(256) void k_convx(const float* __restrict__ x,
                                               char* __restrict__ ABb) {
  int t = blockIdx.x * 256 + threadIdx.x;
  int row = t >> 4, c8 = (t & 15) << 3;
  if (row >= N_NODES) return;
  const float* xp = x + (size_t)row * IN_DIM + c8;
  unsigned short o[8];
#pragma unroll
  for (int i = 0; i < 8; ++i) o[i] = (unsigned short)f2bfu(xp[i]);
  *(short8*)(ABb + (size_t)row * 512 + 256 + c8 * 2) = *(short8*)o;
}

__global__ __launch_bounds__(256) void k_convw1(const float* __restrict__ W1l,
                                                const float* __restrict__ W1r,
                                                unsigned short* __restrict__ Wt1) {
  int n = blockIdx.x, k = threadIdx.x;
  float v = (k < 128) ? W1l[(size_t)k * HID_DIM + n]
                      : W1r[(size_t)(k - 128) * HID_DIM + n];
  Wt1[(size_t)n * 256 + k] = (unsigned short)f2bfu(v);
}

__global__ __launch_bounds__(256) void k_convw2(const float* __restrict__ W2l,
                                                const float* __restrict__ W2r,
                                                unsigned short* __restrict__ Wt2) {
  int n = blockIdx.x, k = threadIdx.x;
  float v = (n < OUT_DIM) ? W2l[(size_t)k * OUT_DIM + n]
                          : W2r[(size_t)k * OUT_DIM + (n - OUT_DIM)];
  Wt2[(size_t)n * 256 + k] = (unsigned short)f2bfu(v);
}

// ---------------- aggregation 1 (bf16 gather, mean) ----------------
// wave per node; 4 edges per iteration: 16-lane group g handles edge e0+g,
// lane q (0..15) in group loads 8 channels (16B). Cross-group shfl reduce.
__global__ __launch_bounds__(256) void k_agg1(char* __restrict__ ABb,
    const int* __restrict__ row_ptr, const int* __restrict__ esrc) {
  int tid = threadIdx.x;
  int node = blockIdx.x * 4 + (tid >> 6);
  int lane = tid & 63;
  int g = lane >> 4;        // 0..3 edge subgroup
  int q = lane & 15;        // channel slot: ch q*8..q*8+7
  int beg = row_ptr[node], end = row_ptr[node + 1];
  float s[8];
#pragma unroll
  for (int j = 0; j < 8; ++j) s[j] = 0.f;

  for (int e0 = beg; e0 < end; e0 += 4) {
    int e = e0 + g;
    if (e < end) {
      int srcn = esrc[e];
      short8 v = *(const short8*)(ABb + (size_t)srcn * 512 + 256 + q * 16);
#pragma unroll
      for (int j = 0; j < 8; ++j)
        s[j] += bfu2f((unsigned short)v[j]);
    }
  }
#pragma unroll
  for (int j = 0; j < 8; ++j) {
    s[j] += __shfl_xor(s[j], 16, 64);
    s[j] += __shfl_xor(s[j], 32, 64);
  }
  float inv = 1.0f / (float)max(end - beg, 1);
  if (lane < 16) {
    unsigned short o[8];
#pragma unroll
    for (int j = 0; j < 8; ++j) o[j] = (unsigned short)f2bfu(s[j] * inv);
    *(short8*)(ABb + (size_t)node * 512 + q * 16) = *(short8*)o;
  }
}

// ---------------- GEMM1: H = relu(AB @ W1cat + b1), bf16 MFMA ----------------
__global__ __launch_bounds__(256) void k_gemm1(
    const char* __restrict__ ABb, const short* __restrict__ Wt1,
    const float* __restrict__ b1, unsigned short* __restrict__ H) {
  __shared__ __align__(16) char As[64 * 512];
  const int tid = threadIdx.x;
  const int w = tid >> 6, lane = tid & 63;
  const int row0 = blockIdx.x * 64;

  {
    const char* gbase = ABb + (size_t)row0 * 512;
#pragma unroll
    for (int i = 0; i < 8; ++i) {
      int o = i * 4096 + w * 1024 + lane * 16;
      int row = o >> 9;
      int kslot = ((o & 511) >> 4) ^ (row & 7);
      GLOAD_LDS16(gbase + row * 512 + kslot * 16, As + i * 4096 + w * 1024);
    }
  }
  __syncthreads();

  f32x4 acc[4][4];
#pragma unroll
  for (int mi = 0; mi < 4; ++mi)
#pragma unroll
    for (int ni = 0; ni < 4; ++ni) acc[mi][ni] = (f32x4){0.f, 0.f, 0.f, 0.f};

  const short* wb = Wt1 + (size_t)(w * 64 + (lane & 15)) * 256 + (lane >> 4) * 8;

  for (int ks = 0; ks < 8; ++ks) {
    short8 af[4], bf[4];
#pragma unroll
    for (int mi = 0; mi < 4; ++mi) {
      int row = mi * 16 + (lane & 15);
      int kslot = (ks * 4 + (lane >> 4)) ^ (row & 7);
      af[mi] = *(const short8*)(As + row * 512 + kslot * 16);
    }
#pragma unroll
    for (int ni = 0; ni < 4; ++ni)
      bf[ni] = *(const short8*)(wb + ni * 16 * 256 + ks * 32);
#pragma unroll
    for (int mi = 0; mi < 4; ++mi)
#pragma unroll
      for (int ni = 0; ni < 4; ++ni)
        acc[mi][ni] = __builtin_amdgcn_mfma_f32_16x16x32_bf16(
            af[mi], bf[ni], acc[mi][ni], 0, 0, 0);
  }

#pragma unroll
  for (int ni = 0; ni < 4; ++ni) {
    int col = w * 64 + ni * 16 + (lane & 15);
    float bv = b1[col];
#pragma unroll
    for (int mi = 0; mi < 4; ++mi) {
      int rbase = row0 + mi * 16 + (lane >> 4) * 4;
#pragma unroll
      for (int r = 0; r < 4; ++r) {
        float v = fmaxf(acc[mi][ni][r] + bv, 0.f);
        H[(size_t)(rbase + r) * 256 + col] = (unsigned short)f2bfu(v);
      }
    }
  }
}

// ---------------- GEMM2: [p2|r2] = H @ W2cat (+b2 on r2), bf16 MFMA ----------
__global__ __launch_bounds__(256) void k_gemm2(
    const char* __restrict__ Hb, const short* __restrict__ Wt2,
    const float* __restrict__ b2, unsigned short* __restrict__ P2,
    float* __restrict__ R2) {
  __shared__ __align__(16) char As[64 * 512];
  const int tid = threadIdx.x;
  const int w = tid >> 6, lane = tid & 63;
  const int row0 = blockIdx.x * 64;

  {
    const char* gbase = Hb + (size_t)row0 * 512;
#pragma unroll
    for (int i = 0; i < 8; ++i) {
      int o = i * 4096 + w * 1024 + lane * 16;
      int row = o >> 9;
      int kslot = ((o & 511) >> 4) ^ (row & 7);
      GLOAD_LDS16(gbase + row * 512 + kslot * 16, As + i * 4096 + w * 1024);
    }
  }
  __syncthreads();

  f32x4 acc[5];
#pragma unroll
  for (int ni = 0; ni < 5; ++ni) acc[ni] = (f32x4){0.f, 0.f, 0.f, 0.f};

  const short* wb = Wt2 + (size_t)(lane & 15) * 256 + (lane >> 4) * 8;
  const int arow = w * 16 + (lane & 15);

  for (int ks = 0; ks < 8; ++ks) {
    int kslot = (ks * 4 + (lane >> 4)) ^ (arow & 7);
    short8 a = *(const short8*)(As + arow * 512 + kslot * 16);
#pragma unroll
    for (int ni = 0; ni < 5; ++ni) {
      short8 bf = *(const short8*)(wb + ni * 16 * 256 + ks * 32);
      acc[ni] = __builtin_amdgcn_mfma_f32_16x16x32_bf16(a, bf, acc[ni], 0, 0, 0);
    }
  }

#pragma unroll
  for (int ni = 0; ni < 5; ++ni) {
    int col = ni * 16 + (lane & 15);
#pragma unroll
    for (int r = 0; r < 4; ++r) {
      int row = row0 + w * 16 + (lane >> 4) * 4 + r;
      float v = acc[ni][r];
      if (col < OUT_DIM) {
        P2[(size_t)row * OUT_DIM + col] = (unsigned short)f2bfu(v);
      } else {
        R2[(size_t)row * OUT_DIM + (col - OUT_DIM)] = v + b2[col - OUT_DIM];
      }
    }
  }
}

// ---------------- agg2 + log_softmax ----------------
// wave per node; 8 edges per iteration in 8-lane groups (g = lane>>3).
// Lane q = lane&7, q<5: loads 8 bf16 channels (16B dwordx4) of P2 row.
// Cross-group reduce via shfl_xor 8/16/32 (q preserved); softmax across q.
__global__ __launch_bounds__(256) void k_agg2(const unsigned short* __restrict__ P2,
    const float* __restrict__ R2, const int* __restrict__ row_ptr,
    const int* __restrict__ esrc, float* __restrict__ out) {
  int tid = threadIdx.x;
  int node = blockIdx.x * 4 + (tid >> 6);
  int lane = tid & 63;
  int g = lane >> 3;        // 0..7 edge slot
  int q = lane & 7;         // 0..4 active: channels q*8..q*8+7
  int beg = row_ptr[node], end = row_ptr[node + 1];
  float s[8];
#pragma unroll
  for (int j = 0; j < 8; ++j) s[j] = 0.f;

  for (int e0 = beg; e0 < end; e0 += 8) {
    int e = e0 + g;
    if (e < end && q < 5) {
      int srcn = esrc[e];
      short8 v = *(const short8*)((const char*)P2 + (size_t)srcn * 80 + q * 16);
#pragma unroll
      for (int j = 0; j < 8; ++j)
        s[j] += bfu2f((unsigned short)v[j]);
    }
  }
  // reduce across the 8 edge groups (q bits preserved by xor 8/16/32)
#pragma unroll
  for (int j = 0; j < 8; ++j) {
    s[j] += __shfl_xor(s[j], 8, 64);
    s[j] += __shfl_xor(s[j], 16, 64);
    s[j] += __shfl_xor(s[j], 32, 64);
  }

  float inv = 1.0f / (float)max(end - beg, 1);
  float v[8];
  float m = -1e30f;
  if (q < 5) {
    const float* rr = R2 + (size_t)node * OUT_DIM + q * 8;
    f32x4 r0 = *(const f32x4*)rr;
    f32x4 r1 = *(const f32x4*)(rr + 4);
#pragma unroll
    for (int j = 0; j < 8; ++j) {
      float rj = (j < 4) ? r0[j] : r1[j - 4];
      v[j] = s[j] * inv + rj;
      m = fmaxf(m, v[j]);
    }
  }
  // softmax reduce across q (xor 1/2/4 within each 8-lane group)
#pragma unroll
  for (int o = 1; o <= 4; o <<= 1) m = fmaxf(m, __shfl_xor(m, o, 64));
  float ex = 0.f;
  if (q < 5) {
#pragma unroll
    for (int j = 0; j < 8; ++j) ex += __expf(v[j] - m);
  }
#pragma unroll
  for (int o = 1; o <= 4; o <<= 1) ex += __shfl_xor(ex, o, 64);
  float ls = __logf(ex) + m;

  if (g == 0 && q < 5) {
    float* op = out + (size_t)node * OUT_DIM + q * 8;
    f32x4 o0, o1;
#pragma unroll
    for (int j = 0; j < 4; ++j) { o0[j] = v[j] - ls; o1[j] = v[j + 4] - ls; }
    *(f32x4*)op = o0;
    *(f32x4*)(op + 4) = o1;
  }
}

extern "C" void kernel_launch(void* const* d_in, const int* in_sizes, int n_in,
                              void* d_out, int out_size, void* d_ws, size_t ws_size,
                              hipStream_t stream) {
  const float* x   = (const float*)d_in[0];
  const int*   ei  = (const int*)d_in[1];
  const float* W1l = (const float*)d_in[2];
  const float* W1r = (const float*)d_in[3];
  const float* b1  = (const float*)d_in[4];
  const float* W2l = (const float*)d_in[5];
  const float* W2r = (const float*)d_in[6];
  const float* b2  = (const float*)d_in[7];
  float* out = (float*)d_out;

  const int* src = ei;
  const int* dst = ei + N_EDGES;

  char* ws = (char*)d_ws;
  int*   cnt     = (int*)(ws + OFF_CNT);
  int*   row_ptr = (int*)(ws + OFF_RP);
  int*   cursor  = (int*)(ws + OFF_CUR);
  int*   esrc    = (int*)(ws + OFF_ESRC);
  char*  ABb     = ws + OFF_AB;
  char*  Hb      = ws + OFF_H;
  unsigned short* Wt1 = (unsigned short*)(ws + OFF_W1T);
  unsigned short* Wt2 = (unsigned short*)(ws + OFF_W2T);
  unsigned short* P2  = (unsigned short*)(ws + OFF_P2);
  float* R2   = (float*)(ws + OFF_R2);
  int*   bsum = (int*)(ws + OFF_BSUM);
  int*   boff = (int*)(ws + OFF_BOFF);

  (void)hipMemsetAsync(cnt, 0, N_NODES * sizeof(int), stream);
  (void)hipMemsetAsync(ABb + (size_t)N_NODES * 512, 0, (M_PAD - N_NODES) * 512,
                       stream);

  k_convx<<<(N_NODES * 16 + 255) / 256, 256, 0, stream>>>(x, ABb);
  k_convw1<<<256, 256, 0, stream>>>(W1l, W1r, Wt1);
  k_convw2<<<80, 256, 0, stream>>>(W2l, W2r, Wt2);

  k_count<<<(N_EDGES + 255) / 256, 256, 0, stream>>>(dst, cnt);
  k_scanA<<<SCAN_BLOCKS, 256, 0, stream>>>(cnt, bsum);
  k_scanB<<<1, 256, 0, stream>>>(bsum, boff, row_ptr);
  k_scanC<<<SCAN_BLOCKS, 256, 0, stream>>>(cnt, boff, row_ptr, cursor);
  k_fill<<<(N_EDGES + 255) / 256, 256, 0, stream>>>(src, dst, cursor, esrc);

  k_agg1<<<N_NODES / 4, 256, 0, stream>>>(ABb, row_ptr, esrc);
  k_gemm1<<<M_PAD / 64, 256, 0, stream>>>(ABb, (const short*)Wt1, b1,
                                          (unsigned short*)Hb);
  k_gemm2<<<M_PAD / 64, 256, 0, stream>>>(Hb, (const short*)Wt2, b2, P2, R2);
  k_agg2<<<N_NODES / 4, 256, 0, stream>>>(P2, R2, row_ptr, esrc, out);
}